// Round 2
// baseline (600.955 us; speedup 1.0000x reference)
//
#include <hip/hip_runtime.h>

// IIR2DResidual: separable bidirectional first-order IIR (a = 0.5, mirror border)
// along W then H on (N=4, H=512, W=512, C=64) fp32 channels-last, then
// out = x + sigmoid(alpha[c]) * (y - x).
//
// Strategy: decay 0.5 => influence dies as 0.5^k. Chunk each scan line into
// T=64 segments with K=16 warm-up on each side (error ~0.5^16 ~ 1e-5; bench
// threshold 6.6e-2). Lane = channel (C=64 = wave width) => every global access
// is a fully coalesced 256B segment in BOTH passes. Window of 96 floats/lane
// lives in registers, processed in-place (x -> yf -> yb).
//
// Boundary exactness: mirror init c0 = x[0] reproduced exactly at w0=0 (warm-up
// steps skipped, carry stays x[0]). Right edge: forward carry held as fixpoint
// for w >= L, which makes the unconditional backward warm-up exact.
//
// ws robustness (R1): never assume ws_size >= 256 MiB. Passes are independent
// per image n, so process images in groups sized to fit ws. If ws can't even
// hold one image (64 MiB), fall back to an in-place V-pass (wave owns a full
// line; no scratch needed).

constexpr int Tc   = 64;            // output chunk per wave
constexpr int Kc   = 16;            // warm-up halo
constexpr int WIN  = Tc + 2 * Kc;   // 96 regs/lane
constexpr int L    = 512;           // scan length (H == W == 512)
constexpr int C    = 64;
constexpr int W    = 512;
constexpr int H    = 512;
constexpr int CHUNKS = L / Tc;      // 8

template<bool VERT, bool COMBINE>
__global__ __launch_bounds__(256)
void iir_scan(const float* __restrict__ in, float* __restrict__ out,
              const float* __restrict__ xres, const float* __restrict__ alpha)
{
    const int lane  = threadIdx.x & 63;
    const int gw    = blockIdx.x * 4 + (threadIdx.x >> 6);   // wave id in group
    const int line  = gw >> 3;                               // / CHUNKS
    const int chunk = gw & (CHUNKS - 1);
    const int w0    = chunk * Tc;

    int base, stride;
    if (VERT) {
        // line = n*W + w ; scan over h. Consecutive lines = consecutive w
        // -> adjacent 256B cache lines across waves.
        const int n = line >> 9;          // / W
        const int w = line & (W - 1);
        base   = (n * H * W + w) * C + lane;
        stride = W * C;
    } else {
        // line = n*H + h ; scan over w.
        base   = line * (W * C) + lane;
        stride = C;
    }
    const float* __restrict__ p = in + base;

    float v[WIN];
    // --- load window (edge-clamped) ---
#pragma unroll
    for (int j = 0; j < WIN; ++j) {
        int w = w0 - Kc + j;
        w = min(max(w, 0), L - 1);
        v[j] = p[w * stride];
    }

    // --- forward scan: yf[t] = 0.5*x[t] + 0.5*yf[t-1], mirror init ---
    float carry = v[0];                  // = x[0] when w0 == 0 (exact mirror)
#pragma unroll
    for (int j = 0; j < WIN; ++j) {
        const int w = w0 - Kc + j;
        if (w >= 0 && w < L)             // wave-uniform predicate
            carry = 0.5f * v[j] + 0.5f * carry;
        v[j] = carry;                    // w >= L: hold yf[L-1] (fixpoint)
    }

    // --- backward scan: yb[t] = 0.5*yf[t] + 0.5*yb[t+1] ---
    float c2 = v[WIN - 1];
#pragma unroll
    for (int j = WIN - 1; j >= Kc; --j) {
        c2 = 0.5f * v[j] + 0.5f * c2;
        v[j] = c2;
    }

    // --- store output region [w0, w0+T) ---
    if (COMBINE) {
        const float mix = 1.0f / (1.0f + __expf(-alpha[lane]));
#pragma unroll
        for (int j = Kc; j < Kc + Tc; ++j) {
            const int w   = w0 + (j - Kc);
            const int idx = base + w * stride;
            const float xv = xres[idx];
            out[idx] = xv + mix * (v[j] - xv);
        }
    } else {
#pragma unroll
        for (int j = Kc; j < Kc + Tc; ++j) {
            const int w = w0 + (j - Kc);
            out[base + w * stride] = v[j];
        }
    }
}

// Emergency V-pass when ws can't hold even one image: operates in-place on y
// (the H-pass result already in d_out). One wave owns one full (n,w) line ->
// reads/writes only its own indices, race-free, zero scratch.
__global__ __launch_bounds__(256)
void iir_vpass_inplace(float* __restrict__ y, const float* __restrict__ xres,
                       const float* __restrict__ alpha)
{
    const int lane = threadIdx.x & 63;
    const int line = blockIdx.x * 4 + (threadIdx.x >> 6);  // n*W + w, 2048 total
    const int n = line >> 9;
    const int w = line & (W - 1);
    const int base   = (n * H * W + w) * C + lane;
    const int stride = W * C;

    // forward, in place
    float carry = y[base];               // mirror init
    for (int h = 0; h < H; ++h) {
        const int idx = base + h * stride;
        carry = 0.5f * y[idx] + 0.5f * carry;
        y[idx] = carry;
    }
    // backward + residual, in place
    const float mix = 1.0f / (1.0f + __expf(-alpha[lane]));
    float c2 = y[base + (H - 1) * stride];
    for (int h = H - 1; h >= 0; --h) {
        const int idx = base + h * stride;
        c2 = 0.5f * y[idx] + 0.5f * c2;
        const float xv = xres[idx];
        y[idx] = xv + mix * (c2 - xv);
    }
}

extern "C" void kernel_launch(void* const* d_in, const int* in_sizes, int n_in,
                              void* d_out, int out_size, void* d_ws, size_t ws_size,
                              hipStream_t stream) {
    const float* x     = (const float*)d_in[0];
    const float* alpha = (const float*)d_in[1];
    float* out = (float*)d_out;
    float* t   = (float*)d_ws;

    const size_t imgElems = (size_t)H * W * C;          // 16,777,216
    const size_t imgBytes = imgElems * sizeof(float);   // 64 MiB
    const int    N        = 4;

    int g = (int)(ws_size / imgBytes);   // images that fit in ws
    if (g > N) g = N;

    if (g >= 1) {
        // Process images in groups of g: H-pass (x->ws), V-pass+combine (ws->out).
        for (int i0 = 0; i0 < N; i0 += g) {
            const int ni = (i0 + g <= N) ? g : (N - i0);
            const size_t off = (size_t)i0 * imgElems;
            // waves = ni*512 lines * 8 chunks; 4 waves/block
            const dim3 grid((unsigned)(ni * 1024)), block(256);
            iir_scan<false, false><<<grid, block, 0, stream>>>(x + off, t, nullptr, nullptr);
            iir_scan<true,  true ><<<grid, block, 0, stream>>>(t, out + off, x + off, alpha);
        }
    } else {
        // No usable scratch: H-pass x -> out, then in-place streaming V-pass.
        const dim3 grid(4096), block(256);
        iir_scan<false, false><<<grid, block, 0, stream>>>(x, out, nullptr, nullptr);
        iir_vpass_inplace<<<dim3(512), block, 0, stream>>>(out, x, alpha);
    }
}